// Round 7
// baseline (339.484 us; speedup 1.0000x reference)
//
#include <hip/hip_runtime.h>
#include <math.h>

// Problem constants (match reference)
#define BATCH 4
#define LSEQ  4096
#define DCH   512
#define NST   16
#define DBLK  8                    // d-channels per block
#define TCH   64                   // chunk length along L
#define CCH   (LSEQ / TCH)         // 64 chunks (= threads per channel)
#define TPB   (DBLK * CCH)         // 512 threads per block
#define NCHAIN (DBLK * NST)        // 128 (d,n) chains per block
#define SSTR  (CCH + 1)            // padded LDS stride (65)

// One block = (batch b, 8-channel slice), full L in-block, one launch:
//   P1: per-thread local scan of one 64-step chunk (x -> registers) -> LDS
//   P2: Hillis-Steele scan over chunks in LDS (v[c] += a^s * v[c-s])
//   P3: entry = inclusive[c-1]; replay chunk from registers; emit y
__global__ __launch_bounds__(TPB, 2) void mamba_one(
    const float* __restrict__ x, const float* __restrict__ A,
    const float* __restrict__ Bm, const float* __restrict__ delta,
    float* __restrict__ y)
{
    __shared__ float v[NCHAIN * SSTR];   // 128 chains x 65 = 33.3 KB
    __shared__ float aT[NCHAIN];         // dA^TCH per chain

    const int bid  = blockIdx.x;             // 0..255
    const int b    = bid / (DCH / DBLK);     // 0..3
    const int dblk = bid % (DCH / DBLK);     // 0..63
    const int d0   = dblk * DBLK;

    const int tid = threadIdx.x;
    const int d   = tid & (DBLK - 1);        // 0..7
    const int c   = tid >> 3;                // 0..63

    const int dg   = d0 + d;                 // global channel
    const float dl = delta[dg];

    float dA[NST], dB[NST], h[NST], xv[TCH];
    const float4* Arow = (const float4*)(A  + dg * NST);
    const float4* Brow = (const float4*)(Bm + dg * NST);
#pragma unroll
    for (int q = 0; q < 4; ++q) {
        float4 a4 = Arow[q], b4 = Brow[q];
        dA[4*q+0] = expf(dl * a4.x);  dB[4*q+0] = dl * b4.x;
        dA[4*q+1] = expf(dl * a4.y);  dB[4*q+1] = dl * b4.y;
        dA[4*q+2] = expf(dl * a4.z);  dB[4*q+2] = dl * b4.z;
        dA[4*q+3] = expf(dl * a4.w);  dB[4*q+3] = dl * b4.w;
    }
#pragma unroll
    for (int n = 0; n < NST; ++n) h[n] = 0.f;

    // chain decay table: thread (d, c=n) publishes dA[n]^64 for chain (d,n)
    if (c < NST) {
        float p = dA[c];
#pragma unroll
        for (int k = 0; k < 6; ++k) p *= p;   // ^64
        aT[d * NST + c] = p;
    }

    // ---- Phase 1: x chunk -> registers; local scan (h0 = 0) ----
    // FULL unroll so xv[] stays in VGPRs (runtime index => scratch).
    const float* xp = x + ((size_t)b * LSEQ + (size_t)c * TCH) * DCH + dg;
#pragma unroll
    for (int t = 0; t < TCH; ++t) {
        xv[t] = xp[(size_t)t * DCH];
#pragma unroll
        for (int n = 0; n < NST; ++n)
            h[n] = fmaf(h[n], dA[n], xv[t] * dB[n]);
    }
#pragma unroll
    for (int n = 0; n < NST; ++n)
        v[(d * NST + n) * SSTR + c] = h[n];

    __syncthreads();

    // ---- Phase 2: Hillis-Steele inclusive scan along c (128 chains) ----
    // thread u handles chains ch0+8k, k=0..15, at chunk cu (consecutive cu
    // across the wave -> conflict-free LDS rows).
    {
        const int cu  = tid & (CCH - 1);
        const int ch0 = tid >> 6;            // 0..7
        float p[16];
#pragma unroll
        for (int k = 0; k < 16; ++k) p[k] = aT[ch0 + 8 * k];

#pragma unroll
        for (int s = 1; s < CCH; s <<= 1) {
            float tmp[16];
#pragma unroll
            for (int k = 0; k < 16; ++k) {
                int addr = (ch0 + 8 * k) * SSTR + cu;
                int src  = addr - ((cu >= s) ? s : 0);   // clamped: never OOB
                float t0 = v[src];
                tmp[k] = (cu >= s) ? t0 : 0.f;
            }
            __syncthreads();
#pragma unroll
            for (int k = 0; k < 16; ++k) {
                int addr = (ch0 + 8 * k) * SSTR + cu;
                v[addr] = fmaf(p[k], tmp[k], v[addr]);
                p[k] *= p[k];
            }
            __syncthreads();
        }
    }

    // ---- Phase 3: entry = inclusive[c-1]; replay from registers; emit y ----
#pragma unroll
    for (int n = 0; n < NST; ++n)
        h[n] = (c > 0) ? v[(d * NST + n) * SSTR + (c - 1)] : 0.f;

    float* yp = y + ((size_t)b * LSEQ + (size_t)c * TCH) * DCH + dg;
#pragma unroll
    for (int t = 0; t < TCH; ++t) {
#pragma unroll
        for (int n = 0; n < NST; ++n)
            h[n] = fmaf(h[n], dA[n], xv[t] * dB[n]);
        float s01 = (h[0]  + h[1])  + (h[2]  + h[3]);
        float s23 = (h[4]  + h[5])  + (h[6]  + h[7]);
        float s45 = (h[8]  + h[9])  + (h[10] + h[11]);
        float s67 = (h[12] + h[13]) + (h[14] + h[15]);
        yp[(size_t)t * DCH] = (s01 + s23) + (s45 + s67);
    }
}

extern "C" void kernel_launch(void* const* d_in, const int* in_sizes, int n_in,
                              void* d_out, int out_size, void* d_ws, size_t ws_size,
                              hipStream_t stream) {
    const float* x     = (const float*)d_in[0];   // (B, L, D)
    const float* A     = (const float*)d_in[1];   // (D, N)
    const float* Bm    = (const float*)d_in[2];   // (D, N)
    const float* delta = (const float*)d_in[3];   // (D,)
    float*       y     = (float*)d_out;           // (B, L, D)

    const int nblocks = BATCH * (DCH / DBLK);     // 256 blocks, 1 per CU
    mamba_one<<<nblocks, TPB, 0, stream>>>(x, A, Bm, delta, y);
}

// Round 8
// 268.579 us; speedup vs baseline: 1.2640x; 1.2640x over previous
//
#include <hip/hip_runtime.h>
#include <math.h>

// Problem constants (match reference)
#define BATCH 4
#define LSEQ  4096
#define DCH   512
#define NST   16
#define DBLK  8                    // d-channels per block
#define TCH   64                   // chunk length along L
#define CCH   (LSEQ / TCH)         // 64 chunks (= threads per channel)
#define TPB   (DBLK * CCH)         // 512 threads per block
#define NCHAIN (DBLK * NST)        // 128 (d,n) chains per block
#define SSTR  72                   // chunk-axis stride: 72 % 32 == 8 -> 2-way max

// One block = (batch b, 8-channel slice), full L in-block, one launch:
//   P1: per-thread local scan of one 64-step chunk (x -> registers) -> LDS
//   P2: Hillis-Steele scan over chunks in LDS (v[c] += a^s * v[c-s])
//   P3: entry = inclusive[c-1]; replay chunk from registers; emit y
// chain index = n*DBLK + d; v[chain*SSTR + c].
__global__ __launch_bounds__(TPB) __attribute__((amdgpu_waves_per_eu(2, 2)))
void mamba_one(
    const float* __restrict__ x, const float* __restrict__ A,
    const float* __restrict__ Bm, const float* __restrict__ delta,
    float* __restrict__ y)
{
    __shared__ float v[NCHAIN * SSTR];   // 128 x 72 x 4B = 36 KB
    __shared__ float aT[NCHAIN];         // dA^TCH per chain

    const int bid  = blockIdx.x;             // 0..255
    const int b    = bid / (DCH / DBLK);     // 0..3
    const int dblk = bid % (DCH / DBLK);     // 0..63
    const int d0   = dblk * DBLK;

    const int tid = threadIdx.x;
    const int d   = tid & (DBLK - 1);        // 0..7
    const int c   = tid >> 3;                // 0..63

    const int dg   = d0 + d;                 // global channel
    const float dl = delta[dg];

    float dA[NST], dB[NST], h[NST], xv[TCH];
    const float4* Arow = (const float4*)(A  + dg * NST);
    const float4* Brow = (const float4*)(Bm + dg * NST);
#pragma unroll
    for (int q = 0; q < 4; ++q) {
        float4 a4 = Arow[q], b4 = Brow[q];
        dA[4*q+0] = expf(dl * a4.x);  dB[4*q+0] = dl * b4.x;
        dA[4*q+1] = expf(dl * a4.y);  dB[4*q+1] = dl * b4.y;
        dA[4*q+2] = expf(dl * a4.z);  dB[4*q+2] = dl * b4.z;
        dA[4*q+3] = expf(dl * a4.w);  dB[4*q+3] = dl * b4.w;
    }
#pragma unroll
    for (int n = 0; n < NST; ++n) h[n] = 0.f;

    // chain decay table: thread (d, c=n<16) publishes dA[n]^64 for chain n*8+d
    if (c < NST) {
        float p = dA[c];
#pragma unroll
        for (int k = 0; k < 6; ++k) p *= p;   // ^64
        aT[c * DBLK + d] = p;
    }

    // ---- Phase 1: x chunk -> registers; local scan (h0 = 0) ----
    // FULL unroll so xv[] stays in VGPRs (runtime index => scratch).
    const float* xp = x + ((size_t)b * LSEQ + (size_t)c * TCH) * DCH + dg;
#pragma unroll
    for (int t = 0; t < TCH; ++t) {
        xv[t] = xp[(size_t)t * DCH];
#pragma unroll
        for (int n = 0; n < NST; ++n)
            h[n] = fmaf(h[n], dA[n], xv[t] * dB[n]);
    }
#pragma unroll
    for (int n = 0; n < NST; ++n)
        v[(n * DBLK + d) * SSTR + c] = h[n];

    __syncthreads();

    // ---- Phase 2: Hillis-Steele inclusive scan along c (128 chains) ----
    // thread u: cu = u&63 (consecutive across wave -> conflict-free),
    // handles chains k*8 + ch0, k = 0..15.
    {
        const int cu  = tid & (CCH - 1);
        const int ch0 = tid >> 6;            // 0..7
        float p[16];
#pragma unroll
        for (int k = 0; k < 16; ++k) p[k] = aT[k * DBLK + ch0];

#pragma unroll
        for (int s = 1; s < CCH; s <<= 1) {
            float tmp[16];
#pragma unroll
            for (int k = 0; k < 16; ++k) {
                int addr = (k * DBLK + ch0) * SSTR + cu;
                int src  = addr - ((cu >= s) ? s : 0);   // clamped: never OOB
                float t0 = v[src];
                tmp[k] = (cu >= s) ? t0 : 0.f;
            }
            __syncthreads();
#pragma unroll
            for (int k = 0; k < 16; ++k) {
                int addr = (k * DBLK + ch0) * SSTR + cu;
                v[addr] = fmaf(p[k], tmp[k], v[addr]);
                p[k] *= p[k];
            }
            __syncthreads();
        }
    }

    // ---- Phase 3: entry = inclusive[c-1]; replay from registers; emit y ----
#pragma unroll
    for (int n = 0; n < NST; ++n) {
        int cm = (c > 0) ? (c - 1) : 0;
        float e = v[(n * DBLK + d) * SSTR + cm];
        h[n] = (c > 0) ? e : 0.f;
    }

    float* yp = y + ((size_t)b * LSEQ + (size_t)c * TCH) * DCH + dg;
#pragma unroll
    for (int t = 0; t < TCH; ++t) {
#pragma unroll
        for (int n = 0; n < NST; ++n)
            h[n] = fmaf(h[n], dA[n], xv[t] * dB[n]);
        float s01 = (h[0]  + h[1])  + (h[2]  + h[3]);
        float s23 = (h[4]  + h[5])  + (h[6]  + h[7]);
        float s45 = (h[8]  + h[9])  + (h[10] + h[11]);
        float s67 = (h[12] + h[13]) + (h[14] + h[15]);
        yp[(size_t)t * DCH] = (s01 + s23) + (s45 + s67);
    }
}

extern "C" void kernel_launch(void* const* d_in, const int* in_sizes, int n_in,
                              void* d_out, int out_size, void* d_ws, size_t ws_size,
                              hipStream_t stream) {
    const float* x     = (const float*)d_in[0];   // (B, L, D)
    const float* A     = (const float*)d_in[1];   // (D, N)
    const float* Bm    = (const float*)d_in[2];   // (D, N)
    const float* delta = (const float*)d_in[3];   // (D,)
    float*       y     = (float*)d_out;           // (B, L, D)

    const int nblocks = BATCH * (DCH / DBLK);     // 256 blocks, 1 per CU
    mamba_one<<<nblocks, TPB, 0, stream>>>(x, A, Bm, delta, y);
}

// Round 9
// 30.557 us; speedup vs baseline: 11.1100x; 8.7896x over previous
//
#include <hip/hip_runtime.h>
#include <math.h>

// Problem constants (match reference)
#define BATCH 4
#define LSEQ  4096
#define DCH   512
#define NST   16
#define DBLK  8                    // d-channels per block
#define TCH   32                   // chunk length along L
#define CCH   (LSEQ / TCH)         // 128 chunks
#define TPB   (DBLK * CCH)         // 1024 threads per block
#define NCHAIN (DBLK * NST)        // 128 (d,n) chains per block
#define SSTR  (CCH + 8)            // 136: mod 32 == 8 -> exact 2-way (free)

// One block = (batch b, 8-channel slice), full L in-block, one launch.
// g-space recurrence: g = g*dA + x  (h = g*dB; y = dot(g,dB) at emit time).
//   P1: x chunk -> registers; local g-scan (g0=0); exit g -> LDS
//   P2: Hillis-Steele scan over 128 chunks in LDS (v[c] += (dA^32)^s * v[c-s])
//   P3: entry = inclusive[c-1]; replay from registers; y = dot(g, dB)
__global__ __launch_bounds__(TPB) void mamba_one(
    const float* __restrict__ x, const float* __restrict__ A,
    const float* __restrict__ Bm, const float* __restrict__ delta,
    float* __restrict__ y)
{
    __shared__ float v[NCHAIN * SSTR];   // 128 x 136 x 4B = 68 KB
    __shared__ float aT[NCHAIN];         // dA^TCH per chain

    // XCD swizzle: adjacent logical blocks share x cache lines -> same XCD L2.
    const int lb   = (blockIdx.x & 7) * 32 + (blockIdx.x >> 3);  // 0..255
    const int b    = lb >> 6;                // 0..3
    const int dgrp = lb & 63;                // 0..63
    const int d0   = dgrp * DBLK;

    const int tid = threadIdx.x;
    const int d   = tid & (DBLK - 1);        // 0..7
    const int c   = tid >> 3;                // 0..127

    const int dg   = d0 + d;                 // global channel
    const float dl = delta[dg];

    float dA[NST], g[NST], xv[TCH];
    const float4* Arow = (const float4*)(A + dg * NST);
#pragma unroll
    for (int q = 0; q < 4; ++q) {
        float4 a4 = Arow[q];
        dA[4*q+0] = expf(dl * a4.x);
        dA[4*q+1] = expf(dl * a4.y);
        dA[4*q+2] = expf(dl * a4.z);
        dA[4*q+3] = expf(dl * a4.w);
    }
#pragma unroll
    for (int n = 0; n < NST; ++n) g[n] = 0.f;

    // chain decay table: thread (d, c=n<16) publishes dA[n]^32 for chain n*8+d
    if (c < NST) {
        float p = dA[c];
#pragma unroll
        for (int k = 0; k < 5; ++k) p *= p;   // ^32
        aT[c * DBLK + d] = p;
    }

    // ---- Phase 1: x chunk -> registers; local g-scan (g0 = 0) ----
    // FULL unroll so xv[] stays in VGPRs (runtime index => scratch).
    const float* xp = x + ((size_t)b * LSEQ + (size_t)c * TCH) * DCH + dg;
#pragma unroll
    for (int t = 0; t < TCH; ++t) {
        xv[t] = xp[(size_t)t * DCH];
#pragma unroll
        for (int n = 0; n < NST; ++n)
            g[n] = fmaf(g[n], dA[n], xv[t]);
    }
#pragma unroll
    for (int n = 0; n < NST; ++n)
        v[(n * DBLK + d) * SSTR + c] = g[n];

    __syncthreads();

    // ---- Phase 2: Hillis-Steele inclusive scan along c (128 chains) ----
    // thread u: cu = u & 127 (consecutive across wave -> 2-way/free),
    // handles chains 8k + ch0, k = 0..15.
    {
        const int cu  = tid & (CCH - 1);
        const int ch0 = tid >> 7;            // 0..7
        float p[16];
#pragma unroll
        for (int k = 0; k < 16; ++k) p[k] = aT[k * DBLK + ch0];

#pragma unroll
        for (int s = 1; s < CCH; s <<= 1) {
            float tmp[16];
#pragma unroll
            for (int k = 0; k < 16; ++k) {
                int addr = (k * DBLK + ch0) * SSTR + cu;
                int src  = addr - ((cu >= s) ? s : 0);   // clamped: never OOB
                float t0 = v[src];
                tmp[k] = (cu >= s) ? t0 : 0.f;
            }
            __syncthreads();
#pragma unroll
            for (int k = 0; k < 16; ++k) {
                int addr = (k * DBLK + ch0) * SSTR + cu;
                v[addr] = fmaf(p[k], tmp[k], v[addr]);
                p[k] *= p[k];
            }
            __syncthreads();
        }
    }

    // ---- Phase 3: entry = inclusive[c-1]; replay; y = dot(g, dB) ----
#pragma unroll
    for (int n = 0; n < NST; ++n) {
        int cm = (c > 0) ? (c - 1) : 0;
        float e = v[(n * DBLK + d) * SSTR + cm];
        g[n] = (c > 0) ? e : 0.f;
    }

    // dB loaded only now (keeps Phase 1/2 register pressure low)
    float dB[NST];
    const float4* Brow = (const float4*)(Bm + dg * NST);
#pragma unroll
    for (int q = 0; q < 4; ++q) {
        float4 b4 = Brow[q];
        dB[4*q+0] = dl * b4.x;
        dB[4*q+1] = dl * b4.y;
        dB[4*q+2] = dl * b4.z;
        dB[4*q+3] = dl * b4.w;
    }

    float* yp = y + ((size_t)b * LSEQ + (size_t)c * TCH) * DCH + dg;
#pragma unroll
    for (int t = 0; t < TCH; ++t) {
#pragma unroll
        for (int n = 0; n < NST; ++n)
            g[n] = fmaf(g[n], dA[n], xv[t]);
        float m[NST];
#pragma unroll
        for (int n = 0; n < NST; ++n) m[n] = g[n] * dB[n];
        float s01 = (m[0]  + m[1])  + (m[2]  + m[3]);
        float s23 = (m[4]  + m[5])  + (m[6]  + m[7]);
        float s45 = (m[8]  + m[9])  + (m[10] + m[11]);
        float s67 = (m[12] + m[13]) + (m[14] + m[15]);
        yp[(size_t)t * DCH] = (s01 + s23) + (s45 + s67);
    }
}

extern "C" void kernel_launch(void* const* d_in, const int* in_sizes, int n_in,
                              void* d_out, int out_size, void* d_ws, size_t ws_size,
                              hipStream_t stream) {
    const float* x     = (const float*)d_in[0];   // (B, L, D)
    const float* A     = (const float*)d_in[1];   // (D, N)
    const float* Bm    = (const float*)d_in[2];   // (D, N)
    const float* delta = (const float*)d_in[3];   // (D,)
    float*       y     = (float*)d_out;           // (B, L, D)

    const int nblocks = BATCH * (DCH / DBLK);     // 256 blocks, 1 per CU
    mamba_one<<<nblocks, TPB, 0, stream>>>(x, A, Bm, delta, y);
}